// Round 10
// baseline (128.066 us; speedup 1.0000x reference)
//
#include <hip/hip_runtime.h>
#include <cstdint>
#include <cstddef>

// Problem constants (match reference file)
#define BB 4
#define MM 8192
#define NN 6890
#define SEGW 64           // candidates per segment = wave width
#define NSEG 108          // ceil(6890/64); candidates padded to NSEG*64
#define NPAD (NSEG * SEGW)  // 6912
#define CHUNKS 4          // MM / MQ
#define MQ 2048           // queries per nn block
#define QT 8              // queries per thread
#define TPB 256
#define NQ (BB * MM)      // 32768 queries
#define FBLK 128          // finalize blocks (x256 threads = NQ)

static constexpr float MIN_T2 = 0.005f * 0.005f;   // MIN_DIST_THRESH^2

// ws layout (bytes):
//   [0, 28311552)            u64 partials[NSEG][NQ]  (d2_bits<<32 | idx)
//   [28311552, 28312064)     float bsum[128]
//   [28312064, 28312576)     int   bmatch[128]
//   [28312576, 28312580)     uint  counter (zeroed by prep)
//   [28312704, 28755136)     float4 cand[BB*NPAD]  (-2x,-2y,-2z, s2/+inf)
#define OFF_BSUM   28311552
#define OFF_BMATCH 28312064
#define OFF_CNT    28312576
#define OFF_CAND   28312704

static __device__ __forceinline__ unsigned long long u64min(
    unsigned long long a, unsigned long long b) { return a < b ? a : b; }

static __device__ __forceinline__ float bcast(float v, int lane) {
    return __int_as_float(__builtin_amdgcn_readlane(__float_as_int(v), lane));
}

// Kernel 0: pack candidates into padded global float4 (-2x,-2y,-2z, s2/+inf).
// Pad entries (n >= NN) and invalid verts get s2=+inf -> e=+inf, never win.
__global__ __launch_bounds__(256) void prep_kernel(
    const float* __restrict__ vt, const int* __restrict__ valid,
    float4* __restrict__ cand, unsigned int* __restrict__ counter)
{
    int i = blockIdx.x * 256 + threadIdx.x;   // 108 blocks x 256 = BB*NPAD
    if (i == 0) *counter = 0;                 // for finalize's last-block
    int b = i / NPAD, n = i - b * NPAD;
    if (i < BB * NPAD) {
        float4 c = make_float4(0.0f, 0.0f, 0.0f, __builtin_inff());
        if (n < NN) {
            const float* p = vt + ((size_t)b * NN + n) * 3;
            float x = p[0], y = p[1], z = p[2];
            float s2 = x * x + y * y + z * z;
            if (valid[b * NN + n] <= 0) s2 = __builtin_inff();
            c = make_float4(-2.0f * x, -2.0f * y, -2.0f * z, s2);
        }
        cand[i] = c;
    }
}

// Kernel 1: per-(batch, m-chunk, n-segment) NN with REGISTER-resident
// candidates: lane l holds candidate (n0+l) in 4 VGPRs (one coalesced load
// per wave), hot loop broadcasts via v_readlane (pure VALU). This removes
// the per-iteration ds_read that oversubscribed the single per-CU LDS pipe
// (VALUBusy pinned ~55% in every LDS variant, R2/R5/R9) and the vector-L1
// latency of R8. NO hot-path atomics (R3), NO grid.sync (R4).
__global__ __launch_bounds__(TPB) void nn_kernel(
    const float* __restrict__ cloth, const float4* __restrict__ cand,
    unsigned long long* __restrict__ partials)
{
    int bid   = blockIdx.x;            // 1728 blocks
    int seg   = bid % NSEG;
    int t2    = bid / NSEG;
    int chunk = t2 & (CHUNKS - 1);
    int b     = t2 >> 2;
    int n0    = seg * SEGW;

    // wave-cooperative candidate load: lane l owns candidate n0+l
    int lane = threadIdx.x & 63;
    float4 cv = cand[(size_t)b * NPAD + n0 + lane];

    float qx[QT], qy[QT], qz[QT], qc2[QT], bd[QT];
    int bi[QT];
    int m0 = chunk * MQ + threadIdx.x;
#pragma unroll
    for (int j = 0; j < QT; j++) {
        int m = m0 + j * TPB;
        const float* p = cloth + ((size_t)b * MM + m) * 3;
        float x = p[0], y = p[1], z = p[2];
        qx[j] = x; qy[j] = y; qz[j] = z;
        qc2[j] = x * x + y * y + z * z;
        bd[j] = __builtin_inff();
        bi[j] = 0;
    }

    // Hot loop: UNFILTERED min in shifted space e = s2 - 2 c.s.
    // Candidate components broadcast lane->SGPR via v_readlane (VALU only).
#pragma unroll 4
    for (int k = 0; k < SEGW; k++) {
        float cx = bcast(cv.x, k), cy = bcast(cv.y, k);
        float cz = bcast(cv.z, k), cw = bcast(cv.w, k);
        int n = n0 + k;
#pragma unroll
        for (int j = 0; j < QT; j++) {
            float e = fmaf(cx, qx[j], fmaf(cy, qy[j], fmaf(cz, qz[j], cw)));
            bool ok = e < bd[j];
            bd[j] = ok ? e : bd[j];
            bi[j] = ok ? n : bi[j];
        }
    }

    // rare fallback: unfiltered min is a too-close candidate -> rescan this
    // segment with the full filter (if the min passes, all candidates do).
#pragma unroll
    for (int j = 0; j < QT; j++) {
        float tmin = MIN_T2 - qc2[j];
        if (bd[j] < tmin) {
            float fb = __builtin_inff(); int fi = 0;
            for (int i = 0; i < SEGW; i++) {
                float cx = bcast(cv.x, i), cy = bcast(cv.y, i);
                float cz = bcast(cv.z, i), cw = bcast(cv.w, i);
                float e = fmaf(cx, qx[j], fmaf(cy, qy[j], fmaf(cz, qz[j], cw)));
                bool ok = (e >= tmin) && (e < fb);
                fb = ok ? e : fb;
                fi = ok ? (n0 + i) : fi;
            }
            bd[j] = fb; bi[j] = fi;
        }
    }

    // coalesced partial store: d2 = e + qc2 >= MIN_T2 > 0 (or +inf), so
    // float bits order correctly as unsigned; low 32 bits = idx tiebreak.
#pragma unroll
    for (int j = 0; j < QT; j++) {
        int q = b * MM + m0 + j * TPB;
        float d2 = bd[j] + qc2[j];
        unsigned long long key =
            ((unsigned long long)__float_as_uint(d2) << 32) | (unsigned)bi[j];
        partials[(size_t)seg * NQ + q] = key;
    }
}

// Kernel 2: per-query u64-min over NSEG segment partials (exact argmin with
// lowest-index tiebreak), gather target, contribution, block-reduce, then
// last-done block folds the 128 block partials into the 4 batch losses.
__global__ __launch_bounds__(256) void finalize_kernel(
    const unsigned long long* __restrict__ partials,
    const int* __restrict__ smpl_idx, const float* __restrict__ sdf,
    const int* __restrict__ cloth_idx, const float* __restrict__ sdf_thresh,
    const float* __restrict__ dist_thresh,
    float* __restrict__ bsum, int* __restrict__ bmatch,
    unsigned int* __restrict__ counter, float* __restrict__ out)
{
    int q = blockIdx.x * 256 + threadIdx.x;   // 128 blocks x 256 = NQ
    int b = q >> 13;
    unsigned long long m0 = ~0ULL, m1 = ~0ULL, m2 = ~0ULL, m3 = ~0ULL;
    for (int s = 0; s < NSEG; s += 4) {       // 108 = 27 x 4
        m0 = u64min(m0, partials[(size_t)(s + 0) * NQ + q]);
        m1 = u64min(m1, partials[(size_t)(s + 1) * NQ + q]);
        m2 = u64min(m2, partials[(size_t)(s + 2) * NQ + q]);
        m3 = u64min(m3, partials[(size_t)(s + 3) * NQ + q]);
    }
    unsigned long long key = u64min(u64min(m0, m1), u64min(m2, m3));

    float d2  = __uint_as_float((unsigned)(key >> 32));
    int   idx = (int)(unsigned)(key & 0xFFFFFFFFu);
    int target = smpl_idx[b * NN + idx];
    int ci0 = cloth_idx[0], ci1 = cloth_idx[1];
    bool match = (target == ci0) || (target == ci1);
    bool near_ = sqrtf(d2) < dist_thresh[0];     // inf -> false
    float s = sdf[q];
    float contrib = near_ ? (match ? fabsf(s) : fabsf(s - sdf_thresh[0])) : 0.0f;
    int mt = match ? 1 : 0;

    for (int off = 32; off > 0; off >>= 1) {
        contrib += __shfl_down(contrib, off, 64);
        mt      |= __shfl_down(mt, off, 64);
    }
    __shared__ float wsum[4];
    __shared__ int   wmat[4];
    __shared__ int   isLast;
    int wave = threadIdx.x >> 6;
    if ((threadIdx.x & 63) == 0) { wsum[wave] = contrib; wmat[wave] = mt; }
    __syncthreads();
    if (threadIdx.x == 0) {
        bsum[blockIdx.x]   = wsum[0] + wsum[1] + wsum[2] + wsum[3];
        bmatch[blockIdx.x] = wmat[0] | wmat[1] | wmat[2] | wmat[3];
        __threadfence();                          // release block partials
        unsigned int old = atomicAdd(counter, 1); // device-scope
        isLast = (old == FBLK - 1) ? 1 : 0;
    }
    __syncthreads();

    if (isLast) {
        __threadfence();                          // acquire others' partials
        if (threadIdx.x < FBLK) {
            int t = threadIdx.x;                  // batch = t>>5, 32 per batch
            float sv = bsum[t];
            int   mv = bmatch[t];
            for (int off = 16; off > 0; off >>= 1) {
                sv += __shfl_down(sv, off, 32);   // 32-wide subgroups
                mv |= __shfl_down(mv, off, 32);
            }
            if ((t & 31) == 0)
                out[t >> 5] = sv * (1.0f / (float)MM) * (mv ? 1.0f : 0.0f);
        }
    }
}

extern "C" void kernel_launch(void* const* d_in, const int* in_sizes, int n_in,
                              void* d_out, int out_size, void* d_ws, size_t ws_size,
                              hipStream_t stream)
{
    const float* sdf         = (const float*)d_in[0];
    const float* cloth       = (const float*)d_in[1];
    const int*   smpl_idx    = (const int*)d_in[2];
    const int*   valid       = (const int*)d_in[3];
    const int*   cloth_idx   = (const int*)d_in[4];
    const float* sdf_thresh  = (const float*)d_in[5];
    const float* dist_thresh = (const float*)d_in[6];
    const float* vt          = (const float*)d_in[7];

    char* ws = (char*)d_ws;
    unsigned long long* partials = (unsigned long long*)ws;
    float*        bsum     = (float*)(ws + OFF_BSUM);
    int*          bmatch   = (int*)(ws + OFF_BMATCH);
    unsigned int* counter  = (unsigned int*)(ws + OFF_CNT);
    float4*       cand     = (float4*)(ws + OFF_CAND);

    prep_kernel<<<(BB * NPAD) / 256, 256, 0, stream>>>(
        vt, valid, cand, counter);
    nn_kernel<<<BB * CHUNKS * NSEG, TPB, 0, stream>>>(cloth, cand, partials);
    finalize_kernel<<<FBLK, 256, 0, stream>>>(
        partials, smpl_idx, sdf, cloth_idx, sdf_thresh, dist_thresh,
        bsum, bmatch, counter, (float*)d_out);
}